// Round 1
// baseline (528.774 us; speedup 1.0000x reference)
//
#include <hip/hip_runtime.h>

typedef __attribute__((ext_vector_type(8))) short s16x8;
typedef __attribute__((ext_vector_type(4))) float f32x4;
typedef unsigned short u16;

#define DEV __device__ __forceinline__

DEV u16 f2b(float f) {
  unsigned u = __builtin_bit_cast(unsigned, f);
  unsigned r = (u + 0x7FFFu + ((u >> 16) & 1u)) >> 16;
  return (u16)r;
}
DEV float b2f(u16 h) { return __builtin_bit_cast(float, (unsigned)h << 16); }
DEV f32x4 mfma16(s16x8 a, s16x8 b, f32x4 c) {
  return __builtin_amdgcn_mfma_f32_16x16x32_bf16(a, b, c, 0, 0, 0);
}
DEV float sigmoidf_(float x) { return 1.0f / (1.0f + expf(-x)); }

// ---------------------------------------------------------------- cast f32->bf16
__global__ __launch_bounds__(256) void cast_k(const float* __restrict__ s, u16* __restrict__ d) {
  size_t i = ((size_t)blockIdx.x * 256 + threadIdx.x) * 4;
  float4 v = *(const float4*)(s + i);
  ushort4 p; p.x = f2b(v.x); p.y = f2b(v.y); p.z = f2b(v.z); p.w = f2b(v.w);
  *(ushort4*)(d + i) = p;
}

// ---------------------------------------------------------------- rmsnorm (row = 1024)
__global__ __launch_bounds__(256) void rmsnorm_k(const float* __restrict__ x, u16* __restrict__ y) {
  const size_t row = blockIdx.x;
  const int tid = threadIdx.x;
  float4 v = ((const float4*)(x + row * 1024))[tid];
  float ss = v.x * v.x + v.y * v.y + v.z * v.z + v.w * v.w;
#pragma unroll
  for (int o = 32; o >= 1; o >>= 1) ss += __shfl_xor(ss, o);
  __shared__ float red[4];
  if ((tid & 63) == 0) red[tid >> 6] = ss;
  __syncthreads();
  float tot = red[0] + red[1] + red[2] + red[3];
  float rn = rsqrtf(tot * (1.0f / 1024.0f) + 1.1920929e-7f);
  ushort4 p;
  p.x = f2b(v.x * rn); p.y = f2b(v.y * rn); p.z = f2b(v.z * rn); p.w = f2b(v.w * rn);
  *(ushort4*)(y + row * 1024 + tid * 4) = p;
}

// ---------------------------------------------------------------- delta (3-phase chunked scan)
// w[t] = exp((T-1-t)*log(clip(sigmoid(logit),1e-6)));  cum = cumsum_t(y*w)
// delta[t] = cum[t-1] / max(w[t],1e-8) * scale
__global__ __launch_bounds__(256)
void delta_partial(const u16* __restrict__ y, const float* __restrict__ logits, float* __restrict__ Pp) {
  const int v = blockIdx.x * 256 + threadIdx.x;
  const int c = blockIdx.y, b = blockIdx.z;
  const float dec = sigmoidf_(logits[v]);
  const float ldc = logf(fmaxf(dec, 1e-6f));
  const u16* yp = y + ((size_t)b * 4096 + c * 128) * 1024 + v;
  float acc = 0.0f;
  for (int t = 0; t < 128; ++t) {
    float wgt = expf((float)(4095 - (c * 128 + t)) * ldc);
    acc += b2f(yp[(size_t)t * 1024]) * wgt;
  }
  Pp[((size_t)b * 32 + c) * 1024 + v] = acc;
}

__global__ __launch_bounds__(256) void delta_scan(float* __restrict__ Pp) {
  const int v = blockIdx.x * 256 + threadIdx.x;
  const int b = blockIdx.y;
  float run = 0.0f;
  for (int c = 0; c < 32; ++c) {
    size_t i = ((size_t)b * 32 + c) * 1024 + v;
    float t = Pp[i];
    Pp[i] = run;
    run += t;
  }
}

__global__ __launch_bounds__(256)
void delta_apply(const float* __restrict__ x0, const u16* __restrict__ y,
                 const float* __restrict__ logits, const float* __restrict__ scale_p,
                 const float* __restrict__ Pp, float* __restrict__ x1) {
  const int v = blockIdx.x * 256 + threadIdx.x;
  const int c = blockIdx.y, b = blockIdx.z;
  const float dec = sigmoidf_(logits[v]);
  const float ldc = logf(fmaxf(dec, 1e-6f));
  const float sc = scale_p[0];
  float carry = Pp[((size_t)b * 32 + c) * 1024 + v];
  size_t base = ((size_t)b * 4096 + c * 128) * 1024 + v;
  for (int t = 0; t < 128; ++t) {
    float wgt = expf((float)(4095 - (c * 128 + t)) * ldc);
    size_t idx = base + (size_t)t * 1024;
    x1[idx] = x0[idx] + carry / fmaxf(wgt, 1e-8f) * sc;
    carry += b2f(y[idx]) * wgt;
  }
}

// ---------------------------------------------------------------- GEMM: C[M,N] = A[M,K] * Bw[N,K]^T
// EPI 0: store bf16 C
// EPI 1: store bf16 transposed into vT[B][256][4096] (requires N tile within 256, M tiles within b)
// EPI 2: Xout = Xin + C*scale (fp32); optional Xb16 = bf16(Xout)
// EPI 3: Cb = bf16(gelu(C + bias[n]))   (exact gelu)
// EPI 4: Xout = Xin * sigmoid(C + bias[n])
#define LDK 72
template <int EPI>
__global__ __launch_bounds__(256)
void gemm_bt(const u16* __restrict__ A, const u16* __restrict__ Bw,
             int M, int N, int K,
             u16* __restrict__ Cb,
             const float* __restrict__ Xin, float* __restrict__ Xout,
             u16* __restrict__ Xb16,
             const float* __restrict__ bias, const float* __restrict__ scale_p) {
  __shared__ u16 sm[2 * 128 * LDK];
  u16* As = sm;
  u16* Bs = sm + 128 * LDK;
  const int tid = threadIdx.x;
  const int n0 = blockIdx.x * 128, m0 = blockIdx.y * 128;
  const int wid = tid >> 6, lane = tid & 63;
  const int wm = (wid >> 1) * 64, wn = (wid & 1) * 64;
  const int lr = lane & 15, lk = (lane >> 4) * 8;
  f32x4 acc[4][4] = {};
  for (int kt = 0; kt < K; kt += 64) {
#pragma unroll
    for (int p = 0; p < 4; ++p) {
      int c = tid + p * 256;
      int row = c >> 3, c8 = (c & 7) * 8;
      *(uint4*)&As[row * LDK + c8] = *(const uint4*)&A[(size_t)(m0 + row) * K + kt + c8];
      *(uint4*)&Bs[row * LDK + c8] = *(const uint4*)&Bw[(size_t)(n0 + row) * K + kt + c8];
    }
    __syncthreads();
#pragma unroll
    for (int kk = 0; kk < 64; kk += 32) {
      s16x8 af[4], bfr[4];
#pragma unroll
      for (int i = 0; i < 4; ++i) af[i] = *(const s16x8*)&As[(wm + i * 16 + lr) * LDK + kk + lk];
#pragma unroll
      for (int j = 0; j < 4; ++j) bfr[j] = *(const s16x8*)&Bs[(wn + j * 16 + lr) * LDK + kk + lk];
#pragma unroll
      for (int i = 0; i < 4; ++i)
#pragma unroll
        for (int j = 0; j < 4; ++j) acc[i][j] = mfma16(af[i], bfr[j], acc[i][j]);
    }
    __syncthreads();
  }
  if constexpr (EPI == 1) {
    u16* CT = sm;  // reuse LDS: 128x136 bf16
#pragma unroll
    for (int i = 0; i < 4; ++i)
#pragma unroll
      for (int j = 0; j < 4; ++j)
#pragma unroll
        for (int r = 0; r < 4; ++r) {
          int ml = wm + i * 16 + (lane >> 4) * 4 + r;
          int nl = wn + j * 16 + lr;
          CT[nl * 136 + ml] = f2b(acc[i][j][r]);
        }
    __syncthreads();
    int nl = tid >> 1, off = (tid & 1) * 64;
    size_t base = ((size_t)(m0 >> 12) * 256 + n0 + nl) * 4096 + (m0 & 4095) + off;
#pragma unroll
    for (int p = 0; p < 8; ++p) *(uint4*)&Cb[base + p * 8] = *(const uint4*)&CT[nl * 136 + off + p * 8];
  } else {
    float sc = (EPI == 2) ? scale_p[0] : 0.0f;
#pragma unroll
    for (int i = 0; i < 4; ++i)
#pragma unroll
      for (int j = 0; j < 4; ++j)
#pragma unroll
        for (int r = 0; r < 4; ++r) {
          int m = m0 + wm + i * 16 + (lane >> 4) * 4 + r;
          int n = n0 + wn + j * 16 + lr;
          float c = acc[i][j][r];
          size_t idx = (size_t)m * N + n;
          if constexpr (EPI == 0) {
            Cb[idx] = f2b(c);
          } else if constexpr (EPI == 2) {
            float v = Xin[idx] + c * sc;
            Xout[idx] = v;
            if (Xb16) Xb16[idx] = f2b(v);
          } else if constexpr (EPI == 3) {
            float g = c + bias[n];
            float ge = 0.5f * g * (1.0f + erff(g * 0.70710678f));
            Cb[idx] = f2b(ge);
          } else {  // EPI 4
            float l = c + bias[n];
            Xout[idx] = Xin[idx] * sigmoidf_(l);
          }
        }
  }
}

// ---------------------------------------------------------------- windowed anti-causal decay attention
// R[b,t,:] = sum_{s>t} (q_t . k_s) * decay^(s-t-1) * v[s,:]
// block: 64 t-rows, 4 waves; s-tiles of 32; early break when decay^(s-t-1) < e^-30 for whole tile.
__global__ __launch_bounds__(256)
void attn_k(const u16* __restrict__ q, const u16* __restrict__ k,
            const u16* __restrict__ vT, u16* __restrict__ R,
            const float* __restrict__ dlogit) {
  const int Tn = 4096, S = 256;
  __shared__ u16 kl[32 * 264];
  __shared__ u16 vtl[256 * 40];
  __shared__ u16 Pl[64 * 40];
  const int t0 = blockIdx.x * 64;
  const int b = blockIdx.y;
  const u16* qb = q + (size_t)b * Tn * S;
  const u16* kb = k + (size_t)b * Tn * S;
  const u16* vb_ = vT + (size_t)b * S * Tn;
  const float dec = sigmoidf_(dlogit[0]);
  const float ld = logf(dec);
  const float nmax = (ld < -1e-9f) ? (-30.0f / ld) : 1e30f;
  const int tid = threadIdx.x, wid = tid >> 6, lane = tid & 63;
  const int lr = lane & 15, lk = (lane >> 4) * 8;
  s16x8 qa[8];
  {
    const u16* qr = qb + (size_t)(t0 + wid * 16 + lr) * S;
#pragma unroll
    for (int kk = 0; kk < 8; ++kk) qa[kk] = *(const s16x8*)&qr[kk * 32 + lk];
  }
  f32x4 racc[4][4] = {};
  for (int s0 = t0; s0 < Tn; s0 += 32) {
    if ((float)(s0 - t0 - 64) > nmax) break;
#pragma unroll
    for (int p = 0; p < 4; ++p) {
      int c = tid + p * 256;
      {
        int row = c >> 5, c8 = (c & 31) * 8;
        *(uint4*)&kl[row * 264 + c8] = *(const uint4*)&kb[(size_t)(s0 + row) * S + c8];
      }
      {
        int d = c >> 2, c8 = (c & 3) * 8;
        *(uint4*)&vtl[d * 40 + c8] = *(const uint4*)&vb_[(size_t)d * Tn + s0 + c8];
      }
    }
    __syncthreads();
    f32x4 sc[2] = {};
#pragma unroll
    for (int kk = 0; kk < 8; ++kk) {
#pragma unroll
      for (int j = 0; j < 2; ++j) {
        s16x8 bf = *(const s16x8*)&kl[(j * 16 + lr) * 264 + kk * 32 + lk];
        sc[j] = mfma16(qa[kk], bf, sc[j]);
      }
    }
#pragma unroll
    for (int j = 0; j < 2; ++j)
#pragma unroll
      for (int r = 0; r < 4; ++r) {
        int tl = wid * 16 + (lane >> 4) * 4 + r;
        int sl = j * 16 + lr;
        int diff = (s0 + sl) - (t0 + tl);
        float pw = (diff > 0) ? expf(ld * (float)(diff - 1)) : 0.0f;
        Pl[tl * 40 + sl] = f2b(sc[j][r] * pw);
      }
    __syncthreads();
    {
      s16x8 pa[4], vv[4];
#pragma unroll
      for (int i = 0; i < 4; ++i) pa[i] = *(const s16x8*)&Pl[(i * 16 + lr) * 40 + lk];
#pragma unroll
      for (int j = 0; j < 4; ++j) vv[j] = *(const s16x8*)&vtl[(wid * 64 + j * 16 + lr) * 40 + lk];
#pragma unroll
      for (int i = 0; i < 4; ++i)
#pragma unroll
        for (int j = 0; j < 4; ++j) racc[i][j] = mfma16(pa[i], vv[j], racc[i][j]);
    }
    __syncthreads();
  }
#pragma unroll
  for (int i = 0; i < 4; ++i)
#pragma unroll
    for (int j = 0; j < 4; ++j)
#pragma unroll
      for (int r = 0; r < 4; ++r) {
        int tl = i * 16 + (lane >> 4) * 4 + r;
        int d = wid * 64 + j * 16 + lr;
        R[((size_t)b * Tn + t0 + tl) * S + d] = f2b(racc[i][j][r]);
      }
}

// ---------------------------------------------------------------- host
extern "C" void kernel_launch(void* const* d_in, const int* in_sizes, int n_in,
                              void* d_out, int out_size, void* d_ws, size_t ws_size,
                              hipStream_t stream) {
  const float* x0 = (const float*)d_in[0];
  const float* Wq = (const float*)d_in[1];
  const float* Wk = (const float*)d_in[2];
  const float* Wv = (const float*)d_in[3];
  const float* Wo = (const float*)d_in[4];
  const float* dlog = (const float*)d_in[5];
  const float* dscale = (const float*)d_in[6];
  const float* th_dec = (const float*)d_in[7];
  const float* th_sc = (const float*)d_in[8];
  const float* ga_dec = (const float*)d_in[9];
  const float* ga_sc = (const float*)d_in[10];
  const float* adw = (const float*)d_in[11];
  const float* auw = (const float*)d_in[12];
  const float* a_upb = (const float*)d_in[13];
  const float* bdw = (const float*)d_in[14];
  const float* buw = (const float*)d_in[15];
  const float* bbias = (const float*)d_in[16];
  const float* bscale = (const float*)d_in[17];

  char* w = (char*)d_ws;
  float* xA = (float*)w;                       // 33,554,432
  u16* y = (u16*)(w + 33554432);               // 16,777,216
  u16* xb = (u16*)(w + 50331648);              // 16,777,216
  u16* qb = (u16*)(w + 67108864);              // 4,194,304
  u16* kb = (u16*)(w + 71303168);              // 4,194,304
  u16* vT = (u16*)(w + 75497472);              // 4,194,304
  u16* Rb = (u16*)(w + 79691776);              // 4,194,304
  u16* gb = (u16*)(w + 83886080);              // 2,097,152
  u16* hb = (u16*)(w + 85983232);              // 33,554,432
  float* Pp = (float*)(w + 119537664);         // 262,144
  u16* Wqb = (u16*)(w + 119799808);            // 524,288
  u16* Wkb = (u16*)(w + 120324096);
  u16* Wvb = (u16*)(w + 120848384);
  u16* Wob = (u16*)(w + 121372672);
  u16* adb = (u16*)(w + 121896960);            // 262,144
  u16* aub = (u16*)(w + 122159104);            // 262,144
  u16* bdb = (u16*)(w + 122421248);            // 4,194,304
  u16* bub = (u16*)(w + 126615552);            // 4,194,304
  float* xB = (float*)d_out;

  // weight casts
  cast_k<<<256, 256, 0, stream>>>(Wq, Wqb);
  cast_k<<<256, 256, 0, stream>>>(Wk, Wkb);
  cast_k<<<256, 256, 0, stream>>>(Wv, Wvb);
  cast_k<<<256, 256, 0, stream>>>(Wo, Wob);
  cast_k<<<128, 256, 0, stream>>>(adw, adb);
  cast_k<<<128, 256, 0, stream>>>(auw, aub);
  cast_k<<<2048, 256, 0, stream>>>(bdw, bdb);
  cast_k<<<2048, 256, 0, stream>>>(buw, bub);

  // ---- stage 1: x1 = x0 + delta(rmsnorm(x0))
  rmsnorm_k<<<8192, 256, 0, stream>>>(x0, y);
  delta_partial<<<dim3(4, 32, 2), 256, 0, stream>>>(y, dlog, Pp);
  delta_scan<<<dim3(4, 2), 256, 0, stream>>>(Pp);
  delta_apply<<<dim3(4, 32, 2), 256, 0, stream>>>(x0, y, dlog, dscale, Pp, xA);

  // ---- stage 2: x2 = x1 + memory(rmsnorm(x1), theta)
  rmsnorm_k<<<8192, 256, 0, stream>>>(xA, y);
  gemm_bt<0><<<dim3(2, 64), 256, 0, stream>>>(y, Wqb, 8192, 256, 1024, qb, nullptr, nullptr, nullptr, nullptr, nullptr);
  gemm_bt<0><<<dim3(2, 64), 256, 0, stream>>>(y, Wkb, 8192, 256, 1024, kb, nullptr, nullptr, nullptr, nullptr, nullptr);
  gemm_bt<1><<<dim3(2, 64), 256, 0, stream>>>(y, Wvb, 8192, 256, 1024, vT, nullptr, nullptr, nullptr, nullptr, nullptr);
  attn_k<<<dim3(64, 2), 256, 0, stream>>>(qb, kb, vT, Rb, th_dec);
  gemm_bt<2><<<dim3(8, 64), 256, 0, stream>>>(Rb, Wob, 8192, 1024, 256, nullptr, xA, xB, xb, nullptr, th_sc);

  // ---- stage 3: x3 = alpha(x2)   (x2 fp32 in xB, bf16 in xb)
  gemm_bt<0><<<dim3(1, 64), 256, 0, stream>>>(xb, adb, 8192, 128, 1024, gb, nullptr, nullptr, nullptr, nullptr, nullptr);
  gemm_bt<4><<<dim3(8, 64), 256, 0, stream>>>(gb, aub, 8192, 1024, 128, nullptr, xB, xA, nullptr, a_upb, nullptr);

  // ---- stage 4: x4 = x3 + beta(rmsnorm(x3))
  rmsnorm_k<<<8192, 256, 0, stream>>>(xA, y);
  gemm_bt<3><<<dim3(16, 64), 256, 0, stream>>>(y, bdb, 8192, 2048, 1024, hb, nullptr, nullptr, nullptr, bbias, nullptr);
  gemm_bt<2><<<dim3(8, 64), 256, 0, stream>>>(hb, bub, 8192, 1024, 2048, nullptr, xA, xB, nullptr, nullptr, bscale);

  // ---- stage 5: out = x4 + memory(rmsnorm(x4), gamma)
  rmsnorm_k<<<8192, 256, 0, stream>>>(xB, y);
  gemm_bt<0><<<dim3(2, 64), 256, 0, stream>>>(y, Wqb, 8192, 256, 1024, qb, nullptr, nullptr, nullptr, nullptr, nullptr);
  gemm_bt<0><<<dim3(2, 64), 256, 0, stream>>>(y, Wkb, 8192, 256, 1024, kb, nullptr, nullptr, nullptr, nullptr, nullptr);
  gemm_bt<1><<<dim3(2, 64), 256, 0, stream>>>(y, Wvb, 8192, 256, 1024, vT, nullptr, nullptr, nullptr, nullptr, nullptr);
  attn_k<<<dim3(64, 2), 256, 0, stream>>>(qb, kb, vT, Rb, ga_dec);
  gemm_bt<2><<<dim3(8, 64), 256, 0, stream>>>(Rb, Wob, 8192, 1024, 256, nullptr, xB, xB, nullptr, nullptr, ga_sc);
}